// Round 4
// baseline (286.823 us; speedup 1.0000x reference)
//
#include <hip/hip_runtime.h>

typedef unsigned int u32;
typedef unsigned short u16;
typedef __attribute__((ext_vector_type(8))) __bf16 bf16x8;
typedef __attribute__((ext_vector_type(4))) float f32x4;

#define NB 16384
#define NM 4096
#define ND 512
#define NOUT 128

// ---------- helpers ----------
__device__ __forceinline__ u16 f2bf(float f) {
  u32 u = __float_as_uint(f);
  u += 0x7FFFu + ((u >> 16) & 1u);   // RNE
  return (u16)(u >> 16);
}

__device__ __forceinline__ void stage16(const u16* g, u16* l) {
  __builtin_amdgcn_global_load_lds((__attribute__((address_space(1))) void*)g,
                                   (__attribute__((address_space(3))) void*)l,
                                   16, 0, 0);
}

__device__ __forceinline__ uint4 pack8(float4 v0, float4 v1) {
  uint4 pk;
  pk.x = (u32)f2bf(v0.x) | ((u32)f2bf(v0.y) << 16);
  pk.y = (u32)f2bf(v0.z) | ((u32)f2bf(v0.w) << 16);
  pk.z = (u32)f2bf(v1.x) | ((u32)f2bf(v1.y) << 16);
  pk.w = (u32)f2bf(v1.z) | ((u32)f2bf(v1.w) << 16);
  return pk;
}

// ---------- merged prep: blocks [0,512) = x, [512,640) = support, [640,672) = head_w ----------
// x_ws  [rbig(128)][kg(64)][row(128)][8]
// s_ws  [mb(32)][kg(64)][m(128)][8]
// hw_ws [slab=(mb*16+kg)][o(128)][8]
__global__ __launch_bounds__(256) void prep_all(const float* __restrict__ x,
                                                const float* __restrict__ s,
                                                const float* __restrict__ hw,
                                                u16* __restrict__ x_ws,
                                                u16* __restrict__ s_ws,
                                                u16* __restrict__ hw_ws,
                                                float* __restrict__ x2,
                                                float* __restrict__ s2) {
  __shared__ uint4 t[2048];   // 32 KB
  const int tid = threadIdx.x, bid = blockIdx.x;
  const int lane = tid & 63, w = tid >> 6;

  if (bid < 640) {
    // ---- x (bid<512) or support (bid>=512): 32-row transpose tile ----
    const int blk = (bid < 512) ? bid : (bid - 512);
    const float* src_m = (bid < 512) ? x : s;
    u16* dst_ws        = (bid < 512) ? x_ws : s_ws;
    float* sq_out      = (bid < 512) ? x2 : s2;
    const int big = blk >> 2, roff = (blk & 3) * 32;

    #pragma unroll
    for (int p = 0; p < 8; ++p) {
      const int row = p * 4 + w;                      // local row 0..31
      const float* src = src_m + (size_t)(blk * 32 + row) * ND + lane * 8;
      float4 v0 = *(const float4*)src;
      float4 v1 = *(const float4*)(src + 4);
      float ss = v0.x*v0.x + v0.y*v0.y + v0.z*v0.z + v0.w*v0.w
               + v1.x*v1.x + v1.y*v1.y + v1.z*v1.z + v1.w*v1.w;
      #pragma unroll
      for (int off = 32; off > 0; off >>= 1) ss += __shfl_down(ss, off);
      if (lane == 0) sq_out[blk * 32 + row] = ss;
      t[lane * 32 + ((row + lane) & 31)] = pack8(v0, v1);   // kg = lane
    }
    __syncthreads();
    #pragma unroll
    for (int p = 0; p < 8; ++p) {
      const int kg = p * 8 + (tid >> 5);
      const int row = tid & 31;
      uint4 pk = t[kg * 32 + ((row + kg) & 31)];
      *(uint4*)&dst_ws[(((size_t)(big * 64 + kg)) * 128 + roff + row) * 8] = pk;
    }
  } else {
    // ---- head_w: m-chunk of 128 ----
    const int blk = bid - 640;
    #pragma unroll
    for (int p = 0; p < 8; ++p) {
      const int o = p * 16 + (tid >> 4);
      const int kg = tid & 15;
      const float* src = hw + (size_t)o * NM + blk * 128 + kg * 8;
      float4 v0 = *(const float4*)src;
      float4 v1 = *(const float4*)(src + 4);
      t[o * 16 + ((kg + o) & 15)] = pack8(v0, v1);
    }
    __syncthreads();
    #pragma unroll
    for (int it = 0; it < 8; ++it) {
      const int kg = it * 2 + (tid >> 7);
      const int o = tid & 127;
      uint4 pk = t[o * 16 + ((kg + o) & 15)];
      *(uint4*)&hw_ws[(((size_t)(blk * 16 + kg)) * 128 + o) * 8] = pk;
    }
  }
}

// ---------- main fused kernel ----------
// grid 512: rb = bid>>2 (128 row-blocks of 128 rows), half = bid&3 (M split 4x, 8 mtiles each)
// block 256 = 4 waves; wave tile 64x64 (4x4 16x16x32 mfma frags)
// LDS 64 KB: Xbuf[2] (8 KB ea) @0, Sbuf[2] (8 KB ea) @8192, Ks 32 KB @16384 (u16 units).
// NOTE: no min-waves launch_bounds — (256,4) forced a 128-reg cap and spilled accs to
// scratch (6x regression, R2). LDS caps occupancy at 2 blocks/CU regardless.
__global__ __launch_bounds__(256)
void rbf_fused(const u16* __restrict__ x_ws, const u16* __restrict__ s_ws,
               const u16* __restrict__ hw_ws, const float* __restrict__ x2,
               const float* __restrict__ s2, const float* __restrict__ gamma_p,
               const float* __restrict__ head_b, const float* __restrict__ scale_p,
               const float* __restrict__ shift_p, float* __restrict__ out)
{
  __shared__ __align__(16) u16 smem[32768];   // 64 KB

  const int tid  = threadIdx.x;
  const int w    = tid >> 6;
  const int lane = tid & 63;
  const int quad = lane >> 4;
  const int l16  = lane & 15;
  const int wr   = w & 1;
  const int wc   = w >> 1;
  const int rb   = blockIdx.x >> 2;
  const int half = blockIdx.x & 3;
  const int b0   = rb * 128;

  const float gamma  = gamma_p[0];
  const float vscale = scale_p[0];
  const float vshift = shift_p[0];

  // per-thread fixed staging assignment: kgl in {w>>1, 2+(w>>1)}, sub = w&1
  const int sub  = w & 1;
  const int kgl0 = w >> 1;
  const int kgl1 = 2 + (w >> 1);
  const u16* xbase = x_ws + (size_t)rb * 65536 + (size_t)(sub * 64 + lane) * 8;
  const u16* sbase = s_ws + (size_t)(half * 8) * 65536 + (size_t)(sub * 64 + lane) * 8;
  const int dst0 = (kgl0 * 128 + sub * 64 + lane) * 8;   // u16 offset within a buf
  const int dst1 = (kgl1 * 128 + sub * 64 + lane) * 8;

  const f32x4 zf = {0.f, 0.f, 0.f, 0.f};
  f32x4 acc_xs[4][4];
  f32x4 acc_out[4][4];
  #pragma unroll
  for (int r = 0; r < 4; ++r)
    #pragma unroll
    for (int c = 0; c < 4; ++c) { acc_xs[r][c] = zf; acc_out[r][c] = zf; }

  auto stage_chunk = [&](int g) {
    const int kc  = g & 15;
    const int mt  = g >> 4;
    const int buf = g & 1;
    const u16* xs = xbase + (size_t)(kc * 4) * 1024;
    const u16* ss = sbase + (size_t)mt * 65536 + (size_t)(kc * 4) * 1024;
    stage16(xs + kgl0 * 1024, &smem[buf * 4096 + dst0]);
    stage16(xs + kgl1 * 1024, &smem[buf * 4096 + dst1]);
    stage16(ss + kgl0 * 1024, &smem[8192 + buf * 4096 + dst0]);
    stage16(ss + kgl1 * 1024, &smem[8192 + buf * 4096 + dst1]);
  };

  auto compute_chunk = [&](int buf) {
    bf16x8 av[4], bv[4];
    #pragma unroll
    for (int r = 0; r < 4; ++r)
      av[r] = *(const bf16x8*)&smem[buf * 4096 + (quad * 128 + wr * 64 + r * 16 + l16) * 8];
    #pragma unroll
    for (int c = 0; c < 4; ++c)
      bv[c] = *(const bf16x8*)&smem[8192 + buf * 4096 + (quad * 128 + wc * 64 + c * 16 + l16) * 8];
    #pragma unroll
    for (int r = 0; r < 4; ++r)
      #pragma unroll
      for (int c = 0; c < 4; ++c)
        acc_xs[r][c] = __builtin_amdgcn_mfma_f32_16x16x32_bf16(av[r], bv[c], acc_xs[r][c], 0, 0, 0);
  };

  stage_chunk(0);
  __syncthreads();

  #pragma unroll 1
  for (int mt = 0; mt < 8; ++mt) {
    const int mtg = half * 8 + mt;
    #pragma unroll 2
    for (int kc = 0; kc < 16; ++kc) {
      const int g = (mt << 4) | kc;
      if (g + 1 < 128) stage_chunk(g + 1);
      compute_chunk(g & 1);
      if (kc < 15) __syncthreads();
    }

    // ---- all-wave exp epilogue: acc_xs -> bf16 K into Ks (GEMM2 A-layout) ----
    {
      float s2v[4];
      #pragma unroll
      for (int c = 0; c < 4; ++c)
        s2v[c] = s2[mtg * 128 + wc * 64 + c * 16 + l16];
      #pragma unroll
      for (int r = 0; r < 4; ++r) {
        const f32x4 xv = *(const f32x4*)&x2[b0 + wr * 64 + r * 16 + quad * 4];
        #pragma unroll
        for (int c = 0; c < 4; ++c) {
          const int cl = wc * 64 + c * 16 + l16;     // m-col 0..127
          const int kg = cl >> 3, e = cl & 7;
          #pragma unroll
          for (int i = 0; i < 4; ++i) {
            const int row = wr * 64 + r * 16 + quad * 4 + i;
            float sq = xv[i] + s2v[c] - 2.0f * acc_xs[r][c][i];
            sq = fmaxf(sq, 0.0f);
            smem[16384 + kg * 1024 + row * 8 + e] = f2bf(__expf(-gamma * sq));
            acc_xs[r][c][i] = 0.0f;
          }
        }
      }
    }
    __syncthreads();

    // ---- GEMM2: acc_out += K(128x128) * hw_tile^T ; B-frags straight from L2 ----
    #pragma unroll
    for (int ks = 0; ks < 4; ++ks) {
      const int kg = ks * 4 + quad;
      bf16x8 a2[4], b2[4];
      #pragma unroll
      for (int r = 0; r < 4; ++r)
        a2[r] = *(const bf16x8*)&smem[16384 + kg * 1024 + (wr * 64 + r * 16 + l16) * 8];
      const size_t slab = (size_t)(mtg * 16 + kg);
      #pragma unroll
      for (int c = 0; c < 4; ++c)
        b2[c] = *(const bf16x8*)(hw_ws + (slab * 128 + wc * 64 + c * 16 + l16) * 8);
      #pragma unroll
      for (int r = 0; r < 4; ++r)
        #pragma unroll
        for (int c = 0; c < 4; ++c)
          acc_out[r][c] = __builtin_amdgcn_mfma_f32_16x16x32_bf16(a2[r], b2[c], acc_out[r][c], 0, 0, 0);
    }
  }

  // ---- final: atomic-accumulate scale*acc (+ bias/shift once, by half==0 blocks) ----
  float addv[4];
  #pragma unroll
  for (int c = 0; c < 4; ++c) {
    const int col = wc * 64 + c * 16 + l16;
    addv[c] = (half == 0) ? (vscale * head_b[col] + vshift) : 0.0f;
  }
  #pragma unroll
  for (int r = 0; r < 4; ++r)
    #pragma unroll
    for (int c = 0; c < 4; ++c) {
      const int col = wc * 64 + c * 16 + l16;
      #pragma unroll
      for (int i = 0; i < 4; ++i) {
        const int row = b0 + wr * 64 + r * 16 + quad * 4 + i;
        atomicAdd(&out[(size_t)row * NOUT + col], vscale * acc_out[r][c][i] + addv[c]);
      }
    }
}

// ---------- launch ----------
extern "C" void kernel_launch(void* const* d_in, const int* in_sizes, int n_in,
                              void* d_out, int out_size, void* d_ws, size_t ws_size,
                              hipStream_t stream) {
  const float* x       = (const float*)d_in[0];
  const float* support = (const float*)d_in[1];
  const float* gamma   = (const float*)d_in[2];
  const float* head_w  = (const float*)d_in[3];
  const float* head_b  = (const float*)d_in[4];
  const float* scale   = (const float*)d_in[5];
  const float* shift   = (const float*)d_in[6];
  float* out = (float*)d_out;

  char* w = (char*)d_ws;
  u16*   x_ws  = (u16*)(w);                       // 16,777,216 B
  u16*   s_ws  = (u16*)(w + 16777216);            //  4,194,304 B
  u16*   hw_ws = (u16*)(w + 20971520);            //  1,048,576 B
  float* x2    = (float*)(w + 22020096);          //     65,536 B
  float* s2    = (float*)(w + 22085632);          //     16,384 B

  hipMemsetAsync(out, 0, (size_t)out_size * sizeof(float), stream);
  prep_all<<<672, 256, 0, stream>>>(x, support, head_w, x_ws, s_ws, hw_ws, x2, s2);
  rbf_fused<<<512, 256, 0, stream>>>(x_ws, s_ws, hw_ws, x2, s2, gamma,
                                     head_b, scale, shift, out);
}

// Round 5
// 262.034 us; speedup vs baseline: 1.0946x; 1.0946x over previous
//
#include <hip/hip_runtime.h>

typedef unsigned int u32;
typedef unsigned short u16;
typedef __attribute__((ext_vector_type(8))) __bf16 bf16x8;
typedef __attribute__((ext_vector_type(4))) float f32x4;

#define NB 16384
#define NM 4096
#define ND 512
#define NOUT 128
#define L2E 1.44269504088896340736f

// ws layout (u16 strides): x_ws [rbig(128)][kg(68)][row(128)][8]  (kg 64..67 = aug)
//                          s_ws [mb(32)][kg(68)][m(128)][8]
//                          hw_ws [slab=(mb*16+kg)][o(128)][8]
#define XKG 68
#define XSTRIDE (XKG * 128 * 8)   // 69632 u16 per rbig / per mb

// ---------- helpers ----------
__device__ __forceinline__ u16 f2bf(float f) {
  u32 u = __float_as_uint(f);
  u += 0x7FFFu + ((u >> 16) & 1u);   // RNE
  return (u16)(u >> 16);
}

__device__ __forceinline__ void stage16(const u16* g, u16* l) {
  __builtin_amdgcn_global_load_lds((__attribute__((address_space(1))) void*)g,
                                   (__attribute__((address_space(3))) void*)l,
                                   16, 0, 0);
}

__device__ __forceinline__ uint4 pack8(float4 v0, float4 v1) {
  uint4 pk;
  pk.x = (u32)f2bf(v0.x) | ((u32)f2bf(v0.y) << 16);
  pk.y = (u32)f2bf(v0.z) | ((u32)f2bf(v0.w) << 16);
  pk.z = (u32)f2bf(v1.x) | ((u32)f2bf(v1.y) << 16);
  pk.w = (u32)f2bf(v1.z) | ((u32)f2bf(v1.w) << 16);
  return pk;
}

// ---------- merged prep ----------
// blocks [0,512): x (32-row transpose tile + aug)     [512,640): support (scaled by -2*gamma*L2E + aug)
// blocks [640,672): head_w transpose                  [672,688): zero d_out
__global__ __launch_bounds__(256) void prep_all(const float* __restrict__ x,
                                                const float* __restrict__ s,
                                                const float* __restrict__ hw,
                                                const float* __restrict__ gamma_p,
                                                u16* __restrict__ x_ws,
                                                u16* __restrict__ s_ws,
                                                u16* __restrict__ hw_ws,
                                                float* __restrict__ out) {
  __shared__ uint4 t[2048];        // 32 KB
  __shared__ float rowss[32];
  const int tid = threadIdx.x, bid = blockIdx.x;
  const int lane = tid & 63, w = tid >> 6;

  if (bid < 640) {
    const bool isx = bid < 512;
    const int blk = isx ? bid : (bid - 512);
    const float* src_m = isx ? x : s;
    u16* dst_ws        = isx ? x_ws : s_ws;
    const float gl   = gamma_p[0] * L2E;
    const float cmul = isx ? 1.0f : (-2.0f * gl);
    const int big = blk >> 2, roff = (blk & 3) * 32;

    #pragma unroll
    for (int p = 0; p < 8; ++p) {
      const int row = p * 4 + w;                      // local row 0..31
      const float* src = src_m + (size_t)(blk * 32 + row) * ND + lane * 8;
      float4 v0 = *(const float4*)src;
      float4 v1 = *(const float4*)(src + 4);
      float ss = v0.x*v0.x + v0.y*v0.y + v0.z*v0.z + v0.w*v0.w
               + v1.x*v1.x + v1.y*v1.y + v1.z*v1.z + v1.w*v1.w;
      #pragma unroll
      for (int off = 32; off > 0; off >>= 1) ss += __shfl_down(ss, off);
      if (lane == 0) rowss[row] = ss;
      v0.x *= cmul; v0.y *= cmul; v0.z *= cmul; v0.w *= cmul;
      v1.x *= cmul; v1.y *= cmul; v1.z *= cmul; v1.w *= cmul;
      t[lane * 32 + ((row + lane) & 31)] = pack8(v0, v1);   // kg = lane
    }
    __syncthreads();
    #pragma unroll
    for (int p = 0; p < 8; ++p) {
      const int kg = p * 8 + (tid >> 5);
      const int row = tid & 31;
      uint4 pk = t[kg * 32 + ((row + kg) & 31)];
      *(uint4*)&dst_ws[(((size_t)(big * XKG + kg)) * 128 + roff + row) * 8] = pk;
    }
    // aug kg 64..67: kg64 = [x2, 1, 0...] (x) or [gl, gl*s2, 0...] (s); kg65..67 = 0
    if (tid < 128) {
      const int kgz = tid >> 5, row = tid & 31;
      uint4 pk = {0u, 0u, 0u, 0u};
      if (kgz == 0) {
        const float r2 = rowss[row];
        pk.x = isx ? ((u32)f2bf(r2) | (0x3F80u << 16))
                   : ((u32)f2bf(gl) | ((u32)f2bf(gl * r2) << 16));
      }
      *(uint4*)&dst_ws[(((size_t)(big * XKG + 64 + kgz)) * 128 + roff + row) * 8] = pk;
    }
  } else if (bid < 672) {
    // ---- head_w: m-chunk of 128 ----
    const int blk = bid - 640;
    #pragma unroll
    for (int p = 0; p < 8; ++p) {
      const int o = p * 16 + (tid >> 4);
      const int kg = tid & 15;
      const float* src = hw + (size_t)o * NM + blk * 128 + kg * 8;
      float4 v0 = *(const float4*)src;
      float4 v1 = *(const float4*)(src + 4);
      t[o * 16 + ((kg + o) & 15)] = pack8(v0, v1);
    }
    __syncthreads();
    #pragma unroll
    for (int it = 0; it < 8; ++it) {
      const int kg = it * 2 + (tid >> 7);
      const int o = tid & 127;
      uint4 pk = t[o * 16 + ((kg + o) & 15)];
      *(uint4*)&hw_ws[(((size_t)(blk * 16 + kg)) * 128 + o) * 8] = pk;
    }
  } else {
    // ---- zero d_out: 16 blocks x 512 KB ----
    float4* o4 = (float4*)out;
    const float4 z = {0.f, 0.f, 0.f, 0.f};
    size_t base = (size_t)(bid - 672) * 32768 + tid;
    #pragma unroll 8
    for (int i = 0; i < 128; ++i) o4[base + (size_t)i * 256] = z;
  }
}

// ---------- main fused kernel ----------
// grid 512: rb = bid>>2 (128 row-blocks of 128 rows), half = bid&3 (M split 4x, 8 mtiles each)
// block 256 = 4 waves; wave tile 64x64 (4x4 16x16x32 mfma frags)
// LDS 64 KB: Xbuf[2] (8 KB ea) @0, Sbuf[2] (8 KB ea) @8192, Ks 32 KB @16384 (u16 units).
// launch_bounds (256,2): cap = 256 total regs/wave. At ~116 VGPR + 128 acc = 244 -> 2 waves/SIMD.
//   (256,4) spills accs to scratch (R2: 2 GB HBM writes, 6x). No bound -> 140 VGPR, 268 total,
//   1 wave/SIMD (R4: occupancy 11.5%, 200 us). ",2" is load-bearing.
__global__ __launch_bounds__(256, 2)
void rbf_fused(const u16* __restrict__ x_ws, const u16* __restrict__ s_ws,
               const u16* __restrict__ hw_ws, const float* __restrict__ head_b,
               const float* __restrict__ scale_p, const float* __restrict__ shift_p,
               float* __restrict__ out)
{
  __shared__ __align__(16) u16 smem[32768];   // 64 KB

  const int tid  = threadIdx.x;
  const int w    = tid >> 6;
  const int lane = tid & 63;
  const int quad = lane >> 4;
  const int l16  = lane & 15;
  const int wr   = w & 1;
  const int wc   = w >> 1;
  const int rb   = blockIdx.x >> 2;
  const int half = blockIdx.x & 3;
  const int b0   = rb * 128;

  const float vscale = scale_p[0];
  const float vshift = shift_p[0];

  // per-thread fixed staging assignment: kgl in {w>>1, 2+(w>>1)}, sub = w&1
  const int sub  = w & 1;
  const int kgl0 = w >> 1;
  const int kgl1 = 2 + (w >> 1);
  const u16* xbase = x_ws + (size_t)rb * XSTRIDE + (size_t)(sub * 64 + lane) * 8;
  const u16* sbase = s_ws + (size_t)(half * 8) * XSTRIDE + (size_t)(sub * 64 + lane) * 8;
  const int dst0 = (kgl0 * 128 + sub * 64 + lane) * 8;   // u16 offset within a buf
  const int dst1 = (kgl1 * 128 + sub * 64 + lane) * 8;

  const f32x4 zf = {0.f, 0.f, 0.f, 0.f};
  f32x4 acc_xs[4][4];
  f32x4 acc_out[4][4];
  #pragma unroll
  for (int r = 0; r < 4; ++r)
    #pragma unroll
    for (int c = 0; c < 4; ++c) { acc_xs[r][c] = zf; acc_out[r][c] = zf; }

  auto stage_chunk = [&](int mt, int kc, int buf) {
    const u16* xs = xbase + (size_t)(kc * 4) * 1024;
    const u16* ss = sbase + (size_t)mt * XSTRIDE + (size_t)(kc * 4) * 1024;
    stage16(xs + kgl0 * 1024, &smem[buf * 4096 + dst0]);
    stage16(xs + kgl1 * 1024, &smem[buf * 4096 + dst1]);
    stage16(ss + kgl0 * 1024, &smem[8192 + buf * 4096 + dst0]);
    stage16(ss + kgl1 * 1024, &smem[8192 + buf * 4096 + dst1]);
  };

  auto compute_chunk = [&](int buf) {
    bf16x8 av[4], bv[4];
    #pragma unroll
    for (int r = 0; r < 4; ++r)
      av[r] = *(const bf16x8*)&smem[buf * 4096 + (quad * 128 + wr * 64 + r * 16 + l16) * 8];
    #pragma unroll
    for (int c = 0; c < 4; ++c)
      bv[c] = *(const bf16x8*)&smem[8192 + buf * 4096 + (quad * 128 + wc * 64 + c * 16 + l16) * 8];
    #pragma unroll
    for (int r = 0; r < 4; ++r)
      #pragma unroll
      for (int c = 0; c < 4; ++c)
        acc_xs[r][c] = __builtin_amdgcn_mfma_f32_16x16x32_bf16(av[r], bv[c], acc_xs[r][c], 0, 0, 0);
  };

  int buf = 0;
  stage_chunk(0, 0, 0);
  __syncthreads();

  #pragma unroll 1
  for (int mt = 0; mt < 8; ++mt) {
    const int mtg = half * 8 + mt;
    #pragma unroll 2
    for (int kc = 0; kc < 17; ++kc) {
      if (!(mt == 7 && kc == 16)) {
        const int nmt = (kc == 16) ? mt + 1 : mt;
        const int nkc = (kc == 16) ? 0 : kc + 1;
        stage_chunk(nmt, nkc, buf ^ 1);
      }
      compute_chunk(buf);
      buf ^= 1;
      if (kc < 16) __syncthreads();
    }

    // ---- epilogue: acc_xs holds gamma*log2e*sqdist; k = min(exp2(-acc), 1) -> bf16(trunc) ----
    #pragma unroll
    for (int r = 0; r < 4; ++r)
      #pragma unroll
      for (int c = 0; c < 4; ++c) {
        const int cl = wc * 64 + c * 16 + l16;     // m-col 0..127
        const int kbase = 16384 + (cl >> 3) * 1024 + (cl & 7);
        #pragma unroll
        for (int i = 0; i < 4; ++i) {
          const int row = wr * 64 + r * 16 + quad * 4 + i;
          float kv = __builtin_amdgcn_exp2f(-acc_xs[r][c][i]);
          kv = fminf(kv, 1.0f);
          smem[kbase + row * 8] = (u16)(__float_as_uint(kv) >> 16);
          acc_xs[r][c][i] = 0.0f;
        }
      }
    __syncthreads();

    // ---- GEMM2: acc_out += K(128x128) * hw_tile^T ; B-frags straight from L2 ----
    #pragma unroll
    for (int ks = 0; ks < 4; ++ks) {
      const int kg = ks * 4 + quad;
      bf16x8 a2[4], b2[4];
      #pragma unroll
      for (int r = 0; r < 4; ++r)
        a2[r] = *(const bf16x8*)&smem[16384 + kg * 1024 + (wr * 64 + r * 16 + l16) * 8];
      const size_t slab = (size_t)(mtg * 16 + kg);
      #pragma unroll
      for (int c = 0; c < 4; ++c)
        b2[c] = *(const bf16x8*)(hw_ws + (slab * 128 + wc * 64 + c * 16 + l16) * 8);
      #pragma unroll
      for (int r = 0; r < 4; ++r)
        #pragma unroll
        for (int c = 0; c < 4; ++c)
          acc_out[r][c] = __builtin_amdgcn_mfma_f32_16x16x32_bf16(a2[r], b2[c], acc_out[r][c], 0, 0, 0);
    }
  }

  // ---- final: atomic-accumulate scale*acc (+ bias/shift once, by half==0 blocks) ----
  float addv[4];
  #pragma unroll
  for (int c = 0; c < 4; ++c) {
    const int col = wc * 64 + c * 16 + l16;
    addv[c] = (half == 0) ? (vscale * head_b[col] + vshift) : 0.0f;
  }
  #pragma unroll
  for (int r = 0; r < 4; ++r)
    #pragma unroll
    for (int c = 0; c < 4; ++c) {
      const int col = wc * 64 + c * 16 + l16;
      #pragma unroll
      for (int i = 0; i < 4; ++i) {
        const int row = b0 + wr * 64 + r * 16 + quad * 4 + i;
        atomicAdd(&out[(size_t)row * NOUT + col], vscale * acc_out[r][c][i] + addv[c]);
      }
    }
}

// ---------- launch ----------
extern "C" void kernel_launch(void* const* d_in, const int* in_sizes, int n_in,
                              void* d_out, int out_size, void* d_ws, size_t ws_size,
                              hipStream_t stream) {
  const float* x       = (const float*)d_in[0];
  const float* support = (const float*)d_in[1];
  const float* gamma   = (const float*)d_in[2];
  const float* head_w  = (const float*)d_in[3];
  const float* head_b  = (const float*)d_in[4];
  const float* scale   = (const float*)d_in[5];
  const float* shift   = (const float*)d_in[6];
  float* out = (float*)d_out;

  char* w = (char*)d_ws;
  u16* x_ws  = (u16*)(w);                         // 17,825,792 B
  u16* s_ws  = (u16*)(w + 17825792);              //  4,456,448 B
  u16* hw_ws = (u16*)(w + 22282240);              //  1,048,576 B (end 23,330,816)

  prep_all<<<688, 256, 0, stream>>>(x, support, head_w, gamma, x_ws, s_ws, hw_ws, out);
  rbf_fused<<<512, 256, 0, stream>>>(x_ws, s_ws, hw_ws, head_b, scale, shift, out);
}

// Round 6
// 213.391 us; speedup vs baseline: 1.3441x; 1.2280x over previous
//
#include <hip/hip_runtime.h>

typedef unsigned int u32;
typedef unsigned short u16;
typedef __attribute__((ext_vector_type(8))) __bf16 bf16x8;
typedef __attribute__((ext_vector_type(4))) float f32x4;

#define NB 16384
#define NM 4096
#define ND 512
#define NOUT 128
#define L2E 1.44269504088896340736f

// ws layout (u16): x_ws [rbig(128)][kg(64)][row(128)][8]
//                  s_ws [mb(32)][kg(64)][m(128)][8]   (pre-scaled by -2*gamma*log2e)
//                  hw_ws [slab=(mb*16+kg)][o(128)][8]
// x2g[16384] = gamma*log2e*||x||^2 ; s2g[4096] = gamma*log2e*||s||^2

// ---------- helpers ----------
__device__ __forceinline__ u16 f2bf(float f) {
  u32 u = __float_as_uint(f);
  u += 0x7FFFu + ((u >> 16) & 1u);   // RNE
  return (u16)(u >> 16);
}

__device__ __forceinline__ void stage16(const u16* g, u16* l) {
  __builtin_amdgcn_global_load_lds((__attribute__((address_space(1))) void*)g,
                                   (__attribute__((address_space(3))) void*)l,
                                   16, 0, 0);
}

__device__ __forceinline__ uint4 pack8(float4 v0, float4 v1) {
  uint4 pk;
  pk.x = (u32)f2bf(v0.x) | ((u32)f2bf(v0.y) << 16);
  pk.y = (u32)f2bf(v0.z) | ((u32)f2bf(v0.w) << 16);
  pk.z = (u32)f2bf(v1.x) | ((u32)f2bf(v1.y) << 16);
  pk.w = (u32)f2bf(v1.z) | ((u32)f2bf(v1.w) << 16);
  return pk;
}

// ---------- merged prep ----------
// blocks [0,512): x tiles    [512,640): support tiles (scaled)    [640,672): head_w    [672,688): zero out
__global__ __launch_bounds__(256) void prep_all(const float* __restrict__ x,
                                                const float* __restrict__ s,
                                                const float* __restrict__ hw,
                                                const float* __restrict__ gamma_p,
                                                u16* __restrict__ x_ws,
                                                u16* __restrict__ s_ws,
                                                u16* __restrict__ hw_ws,
                                                float* __restrict__ x2g,
                                                float* __restrict__ s2g,
                                                float* __restrict__ out) {
  __shared__ uint4 t[2048];        // 32 KB
  const int tid = threadIdx.x, bid = blockIdx.x;
  const int lane = tid & 63, w = tid >> 6;

  if (bid < 640) {
    const bool isx = bid < 512;
    const int blk = isx ? bid : (bid - 512);
    const float* src_m = isx ? x : s;
    u16* dst_ws        = isx ? x_ws : s_ws;
    float* sq_out      = isx ? x2g : s2g;
    const float gl   = gamma_p[0] * L2E;
    const float cmul = isx ? 1.0f : (-2.0f * gl);
    const int big = blk >> 2, roff = (blk & 3) * 32;

    #pragma unroll
    for (int p = 0; p < 8; ++p) {
      const int row = p * 4 + w;                      // local row 0..31
      const float* src = src_m + (size_t)(blk * 32 + row) * ND + lane * 8;
      float4 v0 = *(const float4*)src;
      float4 v1 = *(const float4*)(src + 4);
      float ss = v0.x*v0.x + v0.y*v0.y + v0.z*v0.z + v0.w*v0.w
               + v1.x*v1.x + v1.y*v1.y + v1.z*v1.z + v1.w*v1.w;
      #pragma unroll
      for (int off = 32; off > 0; off >>= 1) ss += __shfl_down(ss, off);
      if (lane == 0) sq_out[blk * 32 + row] = gl * ss;
      v0.x *= cmul; v0.y *= cmul; v0.z *= cmul; v0.w *= cmul;
      v1.x *= cmul; v1.y *= cmul; v1.z *= cmul; v1.w *= cmul;
      t[lane * 32 + ((row + lane) & 31)] = pack8(v0, v1);   // kg = lane
    }
    __syncthreads();
    #pragma unroll
    for (int p = 0; p < 8; ++p) {
      const int kg = p * 8 + (tid >> 5);
      const int row = tid & 31;
      uint4 pk = t[kg * 32 + ((row + kg) & 31)];
      *(uint4*)&dst_ws[(((size_t)(big * 64 + kg)) * 128 + roff + row) * 8] = pk;
    }
  } else if (bid < 672) {
    // ---- head_w: m-chunk of 128 ----
    const int blk = bid - 640;
    #pragma unroll
    for (int p = 0; p < 8; ++p) {
      const int o = p * 16 + (tid >> 4);
      const int kg = tid & 15;
      const float* src = hw + (size_t)o * NM + blk * 128 + kg * 8;
      float4 v0 = *(const float4*)src;
      float4 v1 = *(const float4*)(src + 4);
      t[o * 16 + ((kg + o) & 15)] = pack8(v0, v1);
    }
    __syncthreads();
    #pragma unroll
    for (int it = 0; it < 8; ++it) {
      const int kg = it * 2 + (tid >> 7);
      const int o = tid & 127;
      uint4 pk = t[o * 16 + ((kg + o) & 15)];
      *(uint4*)&hw_ws[(((size_t)(blk * 16 + kg)) * 128 + o) * 8] = pk;
    }
  } else {
    // ---- zero d_out: 16 blocks x 512 KB ----
    float4* o4 = (float4*)out;
    const float4 z = {0.f, 0.f, 0.f, 0.f};
    size_t base = (size_t)(bid - 672) * 32768 + tid;
    #pragma unroll 8
    for (int i = 0; i < 128; ++i) o4[base + (size_t)i * 256] = z;
  }
}

// ---------- main fused kernel ----------
// grid 512. XCD swizzle: xcd = bid&7, half = xcd>>1, rb = (bid>>3)*2 + (xcd&1).
//   All blocks on one XCD share one M-quarter -> its s_ws (1.1 MB) + hw slabs (256 KB)
//   stay resident in that XCD's 4 MB L2.
// block 256 = 4 waves; wave tile 64x64 (4x4 16x16x32 mfma frags)
// LDS 64 KB: Xbuf[2] (8 KB ea) @0, Sbuf[2] (8 KB ea) @8192, Ks 32 KB @16384 (u16 units).
// launch_bounds (256,2): cap = 256 regs/wave total. (256,4) spills accs (R2, 6x slower);
//   no bound -> 140 VGPR + 128 acc = 268 > 256 -> 1 wave/SIMD (R4). ",2" is load-bearing.
// K-loop: affine g, buf = g&1 (R5's carried buf + 17-iter loop broke scheduling: 184 us).
__global__ __launch_bounds__(256, 2)
void rbf_fused(const u16* __restrict__ x_ws, const u16* __restrict__ s_ws,
               const u16* __restrict__ hw_ws, const float* __restrict__ x2g,
               const float* __restrict__ s2g, const float* __restrict__ head_b,
               const float* __restrict__ scale_p, const float* __restrict__ shift_p,
               float* __restrict__ out)
{
  __shared__ __align__(16) u16 smem[32768];   // 64 KB

  const int tid  = threadIdx.x;
  const int w    = tid >> 6;
  const int lane = tid & 63;
  const int quad = lane >> 4;
  const int l16  = lane & 15;
  const int wr   = w & 1;
  const int wc   = w >> 1;
  const int xcd  = blockIdx.x & 7;
  const int rb   = (blockIdx.x >> 3) * 2 + (xcd & 1);
  const int half = xcd >> 1;
  const int b0   = rb * 128;

  const float vscale = scale_p[0];
  const float vshift = shift_p[0];

  // per-thread fixed staging assignment: kgl in {w>>1, 2+(w>>1)}, sub = w&1
  const int sub  = w & 1;
  const int kgl0 = w >> 1;
  const int kgl1 = 2 + (w >> 1);
  const u16* xbase = x_ws + (size_t)rb * 65536 + (size_t)(sub * 64 + lane) * 8;
  const u16* sbase = s_ws + (size_t)(half * 8) * 65536 + (size_t)(sub * 64 + lane) * 8;
  const int dst0 = (kgl0 * 128 + sub * 64 + lane) * 8;   // u16 offset within a buf
  const int dst1 = (kgl1 * 128 + sub * 64 + lane) * 8;

  // hoisted row terms: gamma*log2e*||x||^2 for this wave's 16 rows
  f32x4 x2v[4];
  #pragma unroll
  for (int r = 0; r < 4; ++r)
    x2v[r] = *(const f32x4*)&x2g[b0 + wr * 64 + r * 16 + quad * 4];

  const f32x4 zf = {0.f, 0.f, 0.f, 0.f};
  f32x4 acc_xs[4][4];
  f32x4 acc_out[4][4];
  #pragma unroll
  for (int r = 0; r < 4; ++r)
    #pragma unroll
    for (int c = 0; c < 4; ++c) { acc_xs[r][c] = zf; acc_out[r][c] = zf; }

  auto stage_chunk = [&](int g) {
    const int kc  = g & 15;
    const int mt  = g >> 4;
    const int buf = g & 1;
    const u16* xs = xbase + (size_t)(kc * 4) * 1024;
    const u16* ss = sbase + (size_t)mt * 65536 + (size_t)(kc * 4) * 1024;
    stage16(xs + kgl0 * 1024, &smem[buf * 4096 + dst0]);
    stage16(xs + kgl1 * 1024, &smem[buf * 4096 + dst1]);
    stage16(ss + kgl0 * 1024, &smem[8192 + buf * 4096 + dst0]);
    stage16(ss + kgl1 * 1024, &smem[8192 + buf * 4096 + dst1]);
  };

  auto compute_chunk = [&](int buf) {
    bf16x8 av[4], bv[4];
    #pragma unroll
    for (int r = 0; r < 4; ++r)
      av[r] = *(const bf16x8*)&smem[buf * 4096 + (quad * 128 + wr * 64 + r * 16 + l16) * 8];
    #pragma unroll
    for (int c = 0; c < 4; ++c)
      bv[c] = *(const bf16x8*)&smem[8192 + buf * 4096 + (quad * 128 + wc * 64 + c * 16 + l16) * 8];
    #pragma unroll
    for (int r = 0; r < 4; ++r)
      #pragma unroll
      for (int c = 0; c < 4; ++c)
        acc_xs[r][c] = __builtin_amdgcn_mfma_f32_16x16x32_bf16(av[r], bv[c], acc_xs[r][c], 0, 0, 0);
  };

  stage_chunk(0);
  __syncthreads();

  #pragma unroll 1
  for (int mt = 0; mt < 8; ++mt) {
    const int mtg = half * 8 + mt;
    #pragma unroll 2
    for (int kc = 0; kc < 16; ++kc) {
      const int g = (mt << 4) | kc;
      if (g + 1 < 128) stage_chunk(g + 1);
      compute_chunk(g & 1);
      if (kc < 15) __syncthreads();
    }

    // ---- epilogue: acc_xs = -2*gamma*log2e*xs ; t = acc + x2g + s2g = gamma*log2e*sqdist
    //      k = min(exp2(-t), 1) -> bf16 truncate ----
    {
      float s2v[4];
      #pragma unroll
      for (int c = 0; c < 4; ++c)
        s2v[c] = s2g[mtg * 128 + wc * 64 + c * 16 + l16];
      #pragma unroll
      for (int r = 0; r < 4; ++r)
        #pragma unroll
        for (int c = 0; c < 4; ++c) {
          const int cl = wc * 64 + c * 16 + l16;     // m-col 0..127
          const int kbase = 16384 + (cl >> 3) * 1024 + (cl & 7);
          #pragma unroll
          for (int i = 0; i < 4; ++i) {
            const int row = wr * 64 + r * 16 + quad * 4 + i;
            const float t = acc_xs[r][c][i] + x2v[r][i] + s2v[c];
            float kv = __builtin_amdgcn_exp2f(-t);
            kv = fminf(kv, 1.0f);
            smem[kbase + row * 8] = (u16)(__float_as_uint(kv) >> 16);
            acc_xs[r][c][i] = 0.0f;
          }
        }
    }
    __syncthreads();

    // ---- GEMM2: acc_out += K(128x128) * hw_tile^T ; B-frags straight from L2 ----
    #pragma unroll
    for (int ks = 0; ks < 4; ++ks) {
      const int kg = ks * 4 + quad;
      bf16x8 a2[4], b2[4];
      #pragma unroll
      for (int r = 0; r < 4; ++r)
        a2[r] = *(const bf16x8*)&smem[16384 + kg * 1024 + (wr * 64 + r * 16 + l16) * 8];
      const size_t slab = (size_t)(mtg * 16 + kg);
      #pragma unroll
      for (int c = 0; c < 4; ++c)
        b2[c] = *(const bf16x8*)(hw_ws + (slab * 128 + wc * 64 + c * 16 + l16) * 8);
      #pragma unroll
      for (int r = 0; r < 4; ++r)
        #pragma unroll
        for (int c = 0; c < 4; ++c)
          acc_out[r][c] = __builtin_amdgcn_mfma_f32_16x16x32_bf16(a2[r], b2[c], acc_out[r][c], 0, 0, 0);
    }
    __syncthreads();
  }

  // ---- final: atomic-accumulate scale*acc (+ bias/shift once, by half==0 blocks) ----
  float addv[4];
  #pragma unroll
  for (int c = 0; c < 4; ++c) {
    const int col = wc * 64 + c * 16 + l16;
    addv[c] = (half == 0) ? (vscale * head_b[col] + vshift) : 0.0f;
  }
  #pragma unroll
  for (int r = 0; r < 4; ++r)
    #pragma unroll
    for (int c = 0; c < 4; ++c) {
      const int col = wc * 64 + c * 16 + l16;
      #pragma unroll
      for (int i = 0; i < 4; ++i) {
        const int row = b0 + wr * 64 + r * 16 + quad * 4 + i;
        atomicAdd(&out[(size_t)row * NOUT + col], vscale * acc_out[r][c][i] + addv[c]);
      }
    }
}

// ---------- launch ----------
extern "C" void kernel_launch(void* const* d_in, const int* in_sizes, int n_in,
                              void* d_out, int out_size, void* d_ws, size_t ws_size,
                              hipStream_t stream) {
  const float* x       = (const float*)d_in[0];
  const float* support = (const float*)d_in[1];
  const float* gamma   = (const float*)d_in[2];
  const float* head_w  = (const float*)d_in[3];
  const float* head_b  = (const float*)d_in[4];
  const float* scale   = (const float*)d_in[5];
  const float* shift   = (const float*)d_in[6];
  float* out = (float*)d_out;

  char* w = (char*)d_ws;
  u16*   x_ws  = (u16*)(w);                       // 16,777,216 B
  u16*   s_ws  = (u16*)(w + 16777216);            //  4,194,304 B
  u16*   hw_ws = (u16*)(w + 20971520);            //  1,048,576 B
  float* x2g   = (float*)(w + 22020096);          //     65,536 B
  float* s2g   = (float*)(w + 22085632);          //     16,384 B

  prep_all<<<688, 256, 0, stream>>>(x, support, head_w, gamma,
                                    x_ws, s_ws, hw_ws, x2g, s2g, out);
  rbf_fused<<<512, 256, 0, stream>>>(x_ws, s_ws, hw_ws, x2g, s2g,
                                     head_b, scale, shift, out);
}

// Round 7
// 206.409 us; speedup vs baseline: 1.3896x; 1.0338x over previous
//
#include <hip/hip_runtime.h>

typedef unsigned int u32;
typedef unsigned short u16;
typedef __attribute__((ext_vector_type(8))) __bf16 bf16x8;
typedef __attribute__((ext_vector_type(4))) float f32x4;

#define NB 16384
#define NM 4096
#define ND 512
#define NOUT 128
#define L2E 1.44269504088896340736f

// ws layout (u16): x_ws [rbig(128)][kg(64)][row(128)][8]
//                  s_ws [mb(32)][kg(64)][m(128)][8]   (pre-scaled by -2*gamma*log2e)
//                  hw_ws [slab=(mb*16+kg)][o(128)][8]
// x2g[16384] = gamma*log2e*||x||^2 ; s2g[4096] = gamma*log2e*||s||^2

// ---------- helpers ----------
__device__ __forceinline__ u16 f2bf(float f) {
  u32 u = __float_as_uint(f);
  u += 0x7FFFu + ((u >> 16) & 1u);   // RNE
  return (u16)(u >> 16);
}

__device__ __forceinline__ void stage16(const u16* g, u16* l) {
  __builtin_amdgcn_global_load_lds((__attribute__((address_space(1))) void*)g,
                                   (__attribute__((address_space(3))) void*)l,
                                   16, 0, 0);
}

__device__ __forceinline__ uint4 pack8(float4 v0, float4 v1) {
  uint4 pk;
  pk.x = (u32)f2bf(v0.x) | ((u32)f2bf(v0.y) << 16);
  pk.y = (u32)f2bf(v0.z) | ((u32)f2bf(v0.w) << 16);
  pk.z = (u32)f2bf(v1.x) | ((u32)f2bf(v1.y) << 16);
  pk.w = (u32)f2bf(v1.z) | ((u32)f2bf(v1.w) << 16);
  return pk;
}

// ---------- merged prep (identical to R6 — isolate main-kernel change) ----------
// blocks [0,512): x tiles    [512,640): support tiles (scaled)    [640,672): head_w    [672,688): zero out
__global__ __launch_bounds__(256) void prep_all(const float* __restrict__ x,
                                                const float* __restrict__ s,
                                                const float* __restrict__ hw,
                                                const float* __restrict__ gamma_p,
                                                u16* __restrict__ x_ws,
                                                u16* __restrict__ s_ws,
                                                u16* __restrict__ hw_ws,
                                                float* __restrict__ x2g,
                                                float* __restrict__ s2g,
                                                float* __restrict__ out) {
  __shared__ uint4 t[2048];        // 32 KB
  const int tid = threadIdx.x, bid = blockIdx.x;
  const int lane = tid & 63, w = tid >> 6;

  if (bid < 640) {
    const bool isx = bid < 512;
    const int blk = isx ? bid : (bid - 512);
    const float* src_m = isx ? x : s;
    u16* dst_ws        = isx ? x_ws : s_ws;
    float* sq_out      = isx ? x2g : s2g;
    const float gl   = gamma_p[0] * L2E;
    const float cmul = isx ? 1.0f : (-2.0f * gl);
    const int big = blk >> 2, roff = (blk & 3) * 32;

    #pragma unroll
    for (int p = 0; p < 8; ++p) {
      const int row = p * 4 + w;                      // local row 0..31
      const float* src = src_m + (size_t)(blk * 32 + row) * ND + lane * 8;
      float4 v0 = *(const float4*)src;
      float4 v1 = *(const float4*)(src + 4);
      float ss = v0.x*v0.x + v0.y*v0.y + v0.z*v0.z + v0.w*v0.w
               + v1.x*v1.x + v1.y*v1.y + v1.z*v1.z + v1.w*v1.w;
      #pragma unroll
      for (int off = 32; off > 0; off >>= 1) ss += __shfl_down(ss, off);
      if (lane == 0) sq_out[blk * 32 + row] = gl * ss;
      v0.x *= cmul; v0.y *= cmul; v0.z *= cmul; v0.w *= cmul;
      v1.x *= cmul; v1.y *= cmul; v1.z *= cmul; v1.w *= cmul;
      t[lane * 32 + ((row + lane) & 31)] = pack8(v0, v1);   // kg = lane
    }
    __syncthreads();
    #pragma unroll
    for (int p = 0; p < 8; ++p) {
      const int kg = p * 8 + (tid >> 5);
      const int row = tid & 31;
      uint4 pk = t[kg * 32 + ((row + kg) & 31)];
      *(uint4*)&dst_ws[(((size_t)(big * 64 + kg)) * 128 + roff + row) * 8] = pk;
    }
  } else if (bid < 672) {
    // ---- head_w: m-chunk of 128 ----
    const int blk = bid - 640;
    #pragma unroll
    for (int p = 0; p < 8; ++p) {
      const int o = p * 16 + (tid >> 4);
      const int kg = tid & 15;
      const float* src = hw + (size_t)o * NM + blk * 128 + kg * 8;
      float4 v0 = *(const float4*)src;
      float4 v1 = *(const float4*)(src + 4);
      t[o * 16 + ((kg + o) & 15)] = pack8(v0, v1);
    }
    __syncthreads();
    #pragma unroll
    for (int it = 0; it < 8; ++it) {
      const int kg = it * 2 + (tid >> 7);
      const int o = tid & 127;
      uint4 pk = t[o * 16 + ((kg + o) & 15)];
      *(uint4*)&hw_ws[(((size_t)(blk * 16 + kg)) * 128 + o) * 8] = pk;
    }
  } else {
    // ---- zero d_out: 16 blocks x 512 KB ----
    float4* o4 = (float4*)out;
    const float4 z = {0.f, 0.f, 0.f, 0.f};
    size_t base = (size_t)(bid - 672) * 32768 + tid;
    #pragma unroll 8
    for (int i = 0; i < 128; ++i) o4[base + (size_t)i * 256] = z;
  }
}

// ---------- main fused kernel ----------
// grid 512. XCD swizzle: xcd = bid&7, half = xcd>>1, rb = (bid>>3)*2 + (xcd&1).
// block 256 = 4 waves; wave tile 64x64 (4x4 16x16x32 mfma frags)
// LDS 64 KB: Xbuf[2] @0, Sbuf[2] @8192, Ks 32 KB @16384 (u16 units).
// launch_bounds (256,2) is load-bearing (R2: ",4" spills accs, 6x; R4: no bound -> 1 wave/SIMD).
// Pipelined GEMM2: GEMM2 of mtile mt-1 is folded into kc = {0,4,8,12} of mtile mt's K-loop
// (reads Ks + hw only; Ks reads complete by the kc=14 barrier, before mt's epilogue
// overwrites Ks; post-epilogue barrier orders Ks writes before mt+1's reads). This removes
// the standalone GEMM2 phase + 1 barrier per mtile and raises MFMA per barrier interval ~25%.
__global__ __launch_bounds__(256, 2)
void rbf_fused(const u16* __restrict__ x_ws, const u16* __restrict__ s_ws,
               const u16* __restrict__ hw_ws, const float* __restrict__ x2g,
               const float* __restrict__ s2g, const float* __restrict__ head_b,
               const float* __restrict__ scale_p, const float* __restrict__ shift_p,
               float* __restrict__ out)
{
  __shared__ __align__(16) u16 smem[32768];   // 64 KB

  const int tid  = threadIdx.x;
  const int w    = tid >> 6;
  const int lane = tid & 63;
  const int quad = lane >> 4;
  const int l16  = lane & 15;
  const int wr   = w & 1;
  const int wc   = w >> 1;
  const int xcd  = blockIdx.x & 7;
  const int rb   = (blockIdx.x >> 3) * 2 + (xcd & 1);
  const int half = xcd >> 1;
  const int b0   = rb * 128;

  const float vscale = scale_p[0];
  const float vshift = shift_p[0];

  // per-thread fixed staging assignment: kgl in {w>>1, 2+(w>>1)}, sub = w&1
  const int sub  = w & 1;
  const int kgl0 = w >> 1;
  const int kgl1 = 2 + (w >> 1);
  const u16* xbase = x_ws + (size_t)rb * 65536 + (size_t)(sub * 64 + lane) * 8;
  const u16* sbase = s_ws + (size_t)(half * 8) * 65536 + (size_t)(sub * 64 + lane) * 8;
  const int dst0 = (kgl0 * 128 + sub * 64 + lane) * 8;   // u16 offset within a buf
  const int dst1 = (kgl1 * 128 + sub * 64 + lane) * 8;

  // hoisted row terms: gamma*log2e*||x||^2 for this wave's 16 rows
  f32x4 x2v[4];
  #pragma unroll
  for (int r = 0; r < 4; ++r)
    x2v[r] = *(const f32x4*)&x2g[b0 + wr * 64 + r * 16 + quad * 4];

  const f32x4 zf = {0.f, 0.f, 0.f, 0.f};
  f32x4 acc_xs[4][4];
  f32x4 acc_out[4][4];
  #pragma unroll
  for (int r = 0; r < 4; ++r)
    #pragma unroll
    for (int c = 0; c < 4; ++c) { acc_xs[r][c] = zf; acc_out[r][c] = zf; }

  auto stage_chunk = [&](int g) {
    const int kc  = g & 15;
    const int mt  = g >> 4;
    const int buf = g & 1;
    const u16* xs = xbase + (size_t)(kc * 4) * 1024;
    const u16* ss = sbase + (size_t)mt * 65536 + (size_t)(kc * 4) * 1024;
    stage16(xs + kgl0 * 1024, &smem[buf * 4096 + dst0]);
    stage16(xs + kgl1 * 1024, &smem[buf * 4096 + dst1]);
    stage16(ss + kgl0 * 1024, &smem[8192 + buf * 4096 + dst0]);
    stage16(ss + kgl1 * 1024, &smem[8192 + buf * 4096 + dst1]);
  };

  auto compute_chunk = [&](int buf) {
    bf16x8 av[4], bv[4];
    #pragma unroll
    for (int r = 0; r < 4; ++r)
      av[r] = *(const bf16x8*)&smem[buf * 4096 + (quad * 128 + wr * 64 + r * 16 + l16) * 8];
    #pragma unroll
    for (int c = 0; c < 4; ++c)
      bv[c] = *(const bf16x8*)&smem[8192 + buf * 4096 + (quad * 128 + wc * 64 + c * 16 + l16) * 8];
    #pragma unroll
    for (int r = 0; r < 4; ++r)
      #pragma unroll
      for (int c = 0; c < 4; ++c)
        acc_xs[r][c] = __builtin_amdgcn_mfma_f32_16x16x32_bf16(av[r], bv[c], acc_xs[r][c], 0, 0, 0);
  };

  // one ks-step (4 MFMA) of GEMM2 for mtile mtg2: acc_out += K-slice * hw-slab^T
  auto gemm2_step = [&](int mtg2, int ks) {
    const int kg = ks * 4 + quad;
    bf16x8 a2[4], b2[4];
    #pragma unroll
    for (int r = 0; r < 4; ++r)
      a2[r] = *(const bf16x8*)&smem[16384 + kg * 1024 + (wr * 64 + r * 16 + l16) * 8];
    const size_t slab = (size_t)(mtg2 * 16 + kg);
    #pragma unroll
    for (int c = 0; c < 4; ++c)
      b2[c] = *(const bf16x8*)(hw_ws + (slab * 128 + wc * 64 + c * 16 + l16) * 8);
    #pragma unroll
    for (int r = 0; r < 4; ++r)
      #pragma unroll
      for (int c = 0; c < 4; ++c)
        acc_out[r][c] = __builtin_amdgcn_mfma_f32_16x16x32_bf16(a2[r], b2[c], acc_out[r][c], 0, 0, 0);
  };

  stage_chunk(0);
  __syncthreads();

  #pragma unroll 1
  for (int mt = 0; mt < 8; ++mt) {
    const int mtg = half * 8 + mt;
    #pragma unroll 2
    for (int kc = 0; kc < 16; ++kc) {
      const int g = (mt << 4) | kc;
      if (g + 1 < 128) stage_chunk(g + 1);
      compute_chunk(g & 1);
      if (mt > 0 && (kc & 3) == 0) gemm2_step(mtg - 1, kc >> 2);
      if (kc < 15) __syncthreads();
    }

    // ---- epilogue: acc_xs = -2*gamma*log2e*xs ; t = acc + x2g + s2g = gamma*log2e*sqdist
    //      k = min(exp2(-t), 1) -> bf16 truncate -> Ks (GEMM2 A-layout) ----
    {
      float s2v[4];
      #pragma unroll
      for (int c = 0; c < 4; ++c)
        s2v[c] = s2g[mtg * 128 + wc * 64 + c * 16 + l16];
      #pragma unroll
      for (int r = 0; r < 4; ++r)
        #pragma unroll
        for (int c = 0; c < 4; ++c) {
          const int cl = wc * 64 + c * 16 + l16;     // m-col 0..127
          const int kbase = 16384 + (cl >> 3) * 1024 + (cl & 7);
          #pragma unroll
          for (int i = 0; i < 4; ++i) {
            const int row = wr * 64 + r * 16 + quad * 4 + i;
            const float t = acc_xs[r][c][i] + x2v[r][i] + s2v[c];
            float kv = __builtin_amdgcn_exp2f(-t);
            kv = fminf(kv, 1.0f);
            smem[kbase + row * 8] = (u16)(__float_as_uint(kv) >> 16);
            acc_xs[r][c][i] = 0.0f;
          }
        }
    }
    __syncthreads();
  }

  // ---- drained GEMM2 for the last mtile ----
  #pragma unroll
  for (int ks = 0; ks < 4; ++ks)
    gemm2_step(half * 8 + 7, ks);

  // ---- final: atomic-accumulate scale*acc (+ bias/shift once, by half==0 blocks) ----
  float addv[4];
  #pragma unroll
  for (int c = 0; c < 4; ++c) {
    const int col = wc * 64 + c * 16 + l16;
    addv[c] = (half == 0) ? (vscale * head_b[col] + vshift) : 0.0f;
  }
  #pragma unroll
  for (int r = 0; r < 4; ++r)
    #pragma unroll
    for (int c = 0; c < 4; ++c) {
      const int col = wc * 64 + c * 16 + l16;
      #pragma unroll
      for (int i = 0; i < 4; ++i) {
        const int row = b0 + wr * 64 + r * 16 + quad * 4 + i;
        atomicAdd(&out[(size_t)row * NOUT + col], vscale * acc_out[r][c][i] + addv[c]);
      }
    }
}

// ---------- launch ----------
extern "C" void kernel_launch(void* const* d_in, const int* in_sizes, int n_in,
                              void* d_out, int out_size, void* d_ws, size_t ws_size,
                              hipStream_t stream) {
  const float* x       = (const float*)d_in[0];
  const float* support = (const float*)d_in[1];
  const float* gamma   = (const float*)d_in[2];
  const float* head_w  = (const float*)d_in[3];
  const float* head_b  = (const float*)d_in[4];
  const float* scale   = (const float*)d_in[5];
  const float* shift   = (const float*)d_in[6];
  float* out = (float*)d_out;

  char* w = (char*)d_ws;
  u16*   x_ws  = (u16*)(w);                       // 16,777,216 B
  u16*   s_ws  = (u16*)(w + 16777216);            //  4,194,304 B
  u16*   hw_ws = (u16*)(w + 20971520);            //  1,048,576 B
  float* x2g   = (float*)(w + 22020096);          //     65,536 B
  float* s2g   = (float*)(w + 22085632);          //     16,384 B

  prep_all<<<688, 256, 0, stream>>>(x, support, head_w, gamma,
                                    x_ws, s_ws, hw_ws, x2g, s2g, out);
  rbf_fused<<<512, 256, 0, stream>>>(x_ws, s_ws, hw_ws, x2g, s2g,
                                     head_b, scale, shift, out);
}

// Round 8
// 198.213 us; speedup vs baseline: 1.4470x; 1.0414x over previous
//
#include <hip/hip_runtime.h>

typedef unsigned int u32;
typedef unsigned short u16;
typedef unsigned char u8;
typedef __attribute__((ext_vector_type(8))) __bf16 bf16x8;
typedef __attribute__((ext_vector_type(4))) float f32x4;

#define NB 16384
#define NM 4096
#define ND 512
#define NOUT 128
#define L2E 1.44269504088896340736f

// ws layout: x_ws fp8 [rb(256)][kg64(64)][row(64)][8B]   (8 MB)
//            s_ws fp8 [mb(32)][kg64(64)][m(128)][8B]     (2 MB, pre-scaled by -2*gamma*log2e)
//            hw_ws bf16 [slab=(mb*16+kg)][o(128)][8]     (1 MB)
// x2g[16384] = gamma*log2e*||x||^2 ; s2g[4096] = gamma*log2e*||s||^2  (fp32-exact)

// ---------- helpers ----------
__device__ __forceinline__ u16 f2bf(float f) {
  u32 u = __float_as_uint(f);
  u += 0x7FFFu + ((u >> 16) & 1u);   // RNE
  return (u16)(u >> 16);
}

// manual fp32 -> e4m3fn (RNE, flush |v|<2^-6 to 0; |v| <= ~15 here so no sat needed)
__device__ __forceinline__ u8 f2fp8(float f) {
  u32 u = __float_as_uint(f);
  u32 s = (u >> 24) & 0x80u;
  u32 au = u & 0x7FFFFFFFu;
  if (au < 0x3C800000u) return (u8)s;          // below min normal -> 0
  au += 0x000FFFFFu + ((au >> 20) & 1u);       // RNE to 3 mantissa bits
  u32 e = (au >> 23) - 120u;                   // rebias 127 -> 7
  u32 m = (au >> 20) & 7u;
  return (u8)(s | (e << 3) | m);
}

__device__ __forceinline__ void stage16(const void* g, void* l) {
  __builtin_amdgcn_global_load_lds((__attribute__((address_space(1))) void*)g,
                                   (__attribute__((address_space(3))) void*)l,
                                   16, 0, 0);
}

__device__ __forceinline__ uint4 pack8bf(float4 v0, float4 v1) {
  uint4 pk;
  pk.x = (u32)f2bf(v0.x) | ((u32)f2bf(v0.y) << 16);
  pk.y = (u32)f2bf(v0.z) | ((u32)f2bf(v0.w) << 16);
  pk.z = (u32)f2bf(v1.x) | ((u32)f2bf(v1.y) << 16);
  pk.w = (u32)f2bf(v1.z) | ((u32)f2bf(v1.w) << 16);
  return pk;
}

__device__ __forceinline__ uint2 pack8f8(float4 v0, float4 v1) {
  uint2 pk;
  pk.x = (u32)f2fp8(v0.x) | ((u32)f2fp8(v0.y) << 8) |
         ((u32)f2fp8(v0.z) << 16) | ((u32)f2fp8(v0.w) << 24);
  pk.y = (u32)f2fp8(v1.x) | ((u32)f2fp8(v1.y) << 8) |
         ((u32)f2fp8(v1.z) << 16) | ((u32)f2fp8(v1.w) << 24);
  return pk;
}

// ---------- merged prep ----------
// blocks [0,512): x tiles (fp8)   [512,640): support tiles (fp8, scaled)
// [640,672): head_w (bf16)        [672,688): zero d_out
__global__ __launch_bounds__(256) void prep_all(const float* __restrict__ x,
                                                const float* __restrict__ s,
                                                const float* __restrict__ hw,
                                                const float* __restrict__ gamma_p,
                                                u8*  __restrict__ x_ws,
                                                u8*  __restrict__ s_ws,
                                                u16* __restrict__ hw_ws,
                                                float* __restrict__ x2g,
                                                float* __restrict__ s2g,
                                                float* __restrict__ out) {
  __shared__ uint2 t8[2048];       // 16 KB (x/s transpose, XOR-swizzled)
  __shared__ uint4 t16[2048];      // 32 KB (hw transpose)
  const int tid = threadIdx.x, bid = blockIdx.x;
  const int lane = tid & 63, w = tid >> 6;

  if (bid < 640) {
    const bool isx = bid < 512;
    const int blk = isx ? bid : (bid - 512);
    const float* src_m = isx ? x : s;
    u8*    dst_ws = isx ? x_ws : s_ws;
    float* sq_out = isx ? x2g : s2g;
    const float gl   = gamma_p[0] * L2E;
    const float cmul = isx ? 1.0f : (-2.0f * gl);
    const int big  = isx ? (blk >> 1) : (blk >> 2);
    const int roff = isx ? ((blk & 1) * 32) : ((blk & 3) * 32);
    const int rows = isx ? 64 : 128;

    #pragma unroll
    for (int p = 0; p < 8; ++p) {
      const int row = p * 4 + w;                      // local row 0..31
      const float* src = src_m + (size_t)(blk * 32 + row) * ND + lane * 8;
      float4 v0 = *(const float4*)src;
      float4 v1 = *(const float4*)(src + 4);
      float ss = v0.x*v0.x + v0.y*v0.y + v0.z*v0.z + v0.w*v0.w
               + v1.x*v1.x + v1.y*v1.y + v1.z*v1.z + v1.w*v1.w;
      #pragma unroll
      for (int off = 32; off > 0; off >>= 1) ss += __shfl_down(ss, off);
      if (lane == 0) sq_out[blk * 32 + row] = gl * ss;
      v0.x *= cmul; v0.y *= cmul; v0.z *= cmul; v0.w *= cmul;
      v1.x *= cmul; v1.y *= cmul; v1.z *= cmul; v1.w *= cmul;
      t8[lane * 32 + ((row + lane) & 31)] = pack8f8(v0, v1);   // kg = lane
    }
    __syncthreads();
    #pragma unroll
    for (int p = 0; p < 8; ++p) {
      const int kg = p * 8 + (tid >> 5);
      const int row = tid & 31;
      uint2 pk = t8[kg * 32 + ((row + kg) & 31)];
      *(uint2*)&dst_ws[(((size_t)(big * 64 + kg)) * rows + roff + row) * 8] = pk;
    }
  } else if (bid < 672) {
    // ---- head_w: m-chunk of 128 (bf16) ----
    const int blk = bid - 640;
    #pragma unroll
    for (int p = 0; p < 8; ++p) {
      const int o = p * 16 + (tid >> 4);
      const int kg = tid & 15;
      const float* src = hw + (size_t)o * NM + blk * 128 + kg * 8;
      float4 v0 = *(const float4*)src;
      float4 v1 = *(const float4*)(src + 4);
      t16[o * 16 + ((kg + o) & 15)] = pack8bf(v0, v1);
    }
    __syncthreads();
    #pragma unroll
    for (int it = 0; it < 8; ++it) {
      const int kg = it * 2 + (tid >> 7);
      const int o = tid & 127;
      uint4 pk = t16[o * 16 + ((kg + o) & 15)];
      *(uint4*)&hw_ws[(((size_t)(blk * 16 + kg)) * 128 + o) * 8] = pk;
    }
  } else {
    // ---- zero d_out: 16 blocks x 512 KB ----
    float4* o4 = (float4*)out;
    const float4 z = {0.f, 0.f, 0.f, 0.f};
    size_t base = (size_t)(bid - 672) * 32768 + tid;
    #pragma unroll 8
    for (int i = 0; i < 128; ++i) o4[base + (size_t)i * 256] = z;
  }
}

// ---------- main fused kernel ----------
// grid 1024: xcd = bid&7, half = xcd>>1 (M quarter), rb = (bid>>3)*2 + (xcd&1) (256 blocks of 64 rows).
// block 256 = 4 waves; wave tile 32x64 (2x4 16x16x32 fp8 mfma frags for GEMM1, bf16 for GEMM2).
// LDS 64 KB: X fp8 32 KB @0 (LDS-resident whole kernel -> no X restage, was 267 MB of FETCH);
//            Sbuf[2] 8 KB ea @32768 (2 kc per group, barrier per group);
//            Ks bf16 16 KB @49152.
// launch_bounds (256,2) is load-bearing (R2: ",4" spills accs 6x; R4: no bound -> 1 wave/SIMD).
// GEMM2 of mtile mt-1 folded into even groups of mt's loop (Ks reads done before mt's epilogue
// overwrites Ks; post-epilogue barrier orders Ks writes before mt+1's folded reads).
__global__ __launch_bounds__(256, 2)
void rbf_fused(const u8* __restrict__ x_ws, const u8* __restrict__ s_ws,
               const u16* __restrict__ hw_ws, const float* __restrict__ x2g,
               const float* __restrict__ s2g, const float* __restrict__ head_b,
               const float* __restrict__ scale_p, const float* __restrict__ shift_p,
               float* __restrict__ out)
{
  __shared__ __align__(16) char smem[65536];   // 64 KB

  const int tid  = threadIdx.x;
  const int w    = tid >> 6;
  const int lane = tid & 63;
  const int quad = lane >> 4;
  const int l16  = lane & 15;
  const int wr   = w & 1;    // row half (32 rows)
  const int wc   = w >> 1;   // m / out-col half (64)
  const int xcd  = blockIdx.x & 7;
  const int rb   = (blockIdx.x >> 3) * 2 + (xcd & 1);
  const int half = xcd >> 1;
  const int b0   = rb * 64;

  const float vscale = scale_p[0];
  const float vshift = shift_p[0];

  const u8* xsrc = x_ws + (size_t)rb * 32768;
  const u8* ssrc = s_ws + (size_t)(half * 8) * 65536;

  // ---- stage the whole X slice (32 KB) once ----
  #pragma unroll
  for (int i = 0; i < 8; ++i)
    stage16(xsrc + i * 4096 + tid * 16, smem + i * 4096 + tid * 16);

  f32x4 x2v[2];
  #pragma unroll
  for (int r = 0; r < 2; ++r)
    x2v[r] = *(const f32x4*)&x2g[b0 + wr * 32 + r * 16 + quad * 4];

  const f32x4 zf = {0.f, 0.f, 0.f, 0.f};
  f32x4 acc_xs[2][4];
  f32x4 acc_out[2][4];
  #pragma unroll
  for (int r = 0; r < 2; ++r)
    #pragma unroll
    for (int c = 0; c < 4; ++c) { acc_xs[r][c] = zf; acc_out[r][c] = zf; }

  auto stage_sgrp = [&](int mt, int grp, int buf) {
    const u8* sp = ssrc + (size_t)mt * 65536 + grp * 8192;
    char* dp = smem + 32768 + buf * 8192;
    stage16(sp + tid * 16, dp + tid * 16);
    stage16(sp + 4096 + tid * 16, dp + 4096 + tid * 16);
  };

  // one kc (K=32): 2 A-frags (X resident) x 4 B-frags (Sbuf) -> 8 fp8 MFMA
  auto compute_kc = [&](int kc, int kcL, int buf) {
    long long a[2], b[4];
    #pragma unroll
    for (int r = 0; r < 2; ++r)
      a[r] = *(const long long*)(smem + ((kc * 4 + quad) * 64 + wr * 32 + r * 16 + l16) * 8);
    #pragma unroll
    for (int c = 0; c < 4; ++c)
      b[c] = *(const long long*)(smem + 32768 + buf * 8192 +
                                 ((kcL * 4 + quad) * 128 + wc * 64 + c * 16 + l16) * 8);
    #pragma unroll
    for (int r = 0; r < 2; ++r)
      #pragma unroll
      for (int c = 0; c < 4; ++c)
        acc_xs[r][c] = __builtin_amdgcn_mfma_f32_16x16x32_fp8_fp8(a[r], b[c], acc_xs[r][c], 0, 0, 0);
  };

  // one ks-step (8 bf16 MFMA) of GEMM2: acc_out += Ks-slice * hw-slab^T
  auto gemm2_step = [&](int mtg2, int ks) {
    const int kg = ks * 4 + quad;
    bf16x8 a2[2], b2[4];
    #pragma unroll
    for (int r = 0; r < 2; ++r)
      a2[r] = *(const bf16x8*)(smem + 49152 + (kg * 64 + wr * 32 + r * 16 + l16) * 16);
    const size_t slab = (size_t)(mtg2 * 16 + kg);
    #pragma unroll
    for (int c = 0; c < 4; ++c)
      b2[c] = *(const bf16x8*)(hw_ws + (slab * 128 + wc * 64 + c * 16 + l16) * 8);
    #pragma unroll
    for (int r = 0; r < 2; ++r)
      #pragma unroll
      for (int c = 0; c < 4; ++c)
        acc_out[r][c] = __builtin_amdgcn_mfma_f32_16x16x32_bf16(a2[r], b2[c], acc_out[r][c], 0, 0, 0);
  };

  stage_sgrp(0, 0, 0);
  __syncthreads();

  #pragma unroll 1
  for (int mt = 0; mt < 8; ++mt) {
    const int mtg = half * 8 + mt;
    #pragma unroll
    for (int grp = 0; grp < 8; ++grp) {
      if (grp < 7)      stage_sgrp(mt, grp + 1, (grp + 1) & 1);
      else if (mt < 7)  stage_sgrp(mt + 1, 0, 0);
      compute_kc(grp * 2,     0, grp & 1);
      compute_kc(grp * 2 + 1, 1, grp & 1);
      if (mt > 0 && (grp & 1) == 0) gemm2_step(mtg - 1, grp >> 1);
      if (grp < 7) __syncthreads();
    }

    // ---- epilogue: t = acc + x2g + s2g = gamma*log2e*sqdist ; k = min(exp2(-t),1) -> bf16 Ks ----
    {
      float s2v[4];
      #pragma unroll
      for (int c = 0; c < 4; ++c)
        s2v[c] = s2g[mtg * 128 + wc * 64 + c * 16 + l16];
      #pragma unroll
      for (int r = 0; r < 2; ++r)
        #pragma unroll
        for (int c = 0; c < 4; ++c) {
          const int cl = wc * 64 + c * 16 + l16;     // m-col 0..127
          char* kbase = smem + 49152 + (cl >> 3) * 1024 + (cl & 7) * 2;
          #pragma unroll
          for (int i = 0; i < 4; ++i) {
            const int row = wr * 32 + r * 16 + quad * 4 + i;
            const float t = acc_xs[r][c][i] + x2v[r][i] + s2v[c];
            float kv = __builtin_amdgcn_exp2f(-t);
            kv = fminf(kv, 1.0f);
            *(u16*)(kbase + row * 16) = (u16)(__float_as_uint(kv) >> 16);
            acc_xs[r][c][i] = 0.0f;
          }
        }
    }
    __syncthreads();
  }

  // ---- drained GEMM2 for the last mtile ----
  #pragma unroll
  for (int ks = 0; ks < 4; ++ks)
    gemm2_step(half * 8 + 7, ks);

  // ---- final: atomic-accumulate scale*acc (+ bias/shift once, by half==0 blocks) ----
  float addv[4];
  #pragma unroll
  for (int c = 0; c < 4; ++c) {
    const int col = wc * 64 + c * 16 + l16;
    addv[c] = (half == 0) ? (vscale * head_b[col] + vshift) : 0.0f;
  }
  #pragma unroll
  for (int r = 0; r < 2; ++r)
    #pragma unroll
    for (int c = 0; c < 4; ++c) {
      const int col = wc * 64 + c * 16 + l16;
      #pragma unroll
      for (int i = 0; i < 4; ++i) {
        const int row = b0 + wr * 32 + r * 16 + quad * 4 + i;
        atomicAdd(&out[(size_t)row * NOUT + col], vscale * acc_out[r][c][i] + addv[c]);
      }
    }
}

// ---------- launch ----------
extern "C" void kernel_launch(void* const* d_in, const int* in_sizes, int n_in,
                              void* d_out, int out_size, void* d_ws, size_t ws_size,
                              hipStream_t stream) {
  const float* x       = (const float*)d_in[0];
  const float* support = (const float*)d_in[1];
  const float* gamma   = (const float*)d_in[2];
  const float* head_w  = (const float*)d_in[3];
  const float* head_b  = (const float*)d_in[4];
  const float* scale   = (const float*)d_in[5];
  const float* shift   = (const float*)d_in[6];
  float* out = (float*)d_out;

  char* w = (char*)d_ws;
  u8*    x_ws  = (u8*)(w);                        //  8,388,608 B
  u8*    s_ws  = (u8*)(w + 8388608);              //  2,097,152 B
  u16*   hw_ws = (u16*)(w + 10485760);            //  1,048,576 B
  float* x2g   = (float*)(w + 11534336);          //     65,536 B
  float* s2g   = (float*)(w + 11599872);          //     16,384 B

  prep_all<<<688, 256, 0, stream>>>(x, support, head_w, gamma,
                                    x_ws, s_ws, hw_ws, x2g, s2g, out);
  rbf_fused<<<1024, 256, 0, stream>>>(x_ws, s_ws, hw_ws, x2g, s2g,
                                      head_b, scale, shift, out);
}